// Round 3
// baseline (2549.608 us; speedup 1.0000x reference)
//
#include <hip/hip_runtime.h>
#include <hip/hip_bf16.h>
#include <math.h>

#define T_   64
#define B_   2048
#define OBS_ 48
#define H_   256
#define M1_  512
#define M2_  256
#define A_   12
#define BH_  (B_ * H_)
#define KP_  320   // padded K for scan: 64 (x, padded from 48) + 256 (h)

typedef unsigned short u16;
typedef __attribute__((ext_vector_type(8))) short bf16x8;
typedef __attribute__((ext_vector_type(4))) float f32x4;

static __device__ __forceinline__ u16 f2b(float f) {
    __hip_bfloat16 h = __float2bfloat16(f);
    return *reinterpret_cast<u16*>(&h);
}
static __device__ __forceinline__ float b2f(u16 u) {
    union { unsigned u32; float f; } v; v.u32 = ((unsigned)u) << 16; return v.f;
}
static __device__ __forceinline__ float sigm(float x) {
    return 1.0f / (1.0f + __expf(-x));
}
static __device__ __forceinline__ float tanh_fast(float x) {
    x = fminf(fmaxf(x, -15.0f), 15.0f);
    float e = __expf(2.0f * x);
    return (e - 1.0f) / (e + 1.0f);
}
static __device__ __forceinline__ float elu(float x) {
    return x > 0.0f ? x : (__expf(x) - 1.0f);
}

// ---------------------------------------------------------------------------
// Pre-pass kernels
// ---------------------------------------------------------------------------
__global__ void prep_xpad(const float* __restrict__ x, u16* __restrict__ xpad) {
    const int i = blockIdx.x * 256 + threadIdx.x;   // over T*B*64
    const int r = i >> 6, k = i & 63;
    xpad[i] = (k < OBS_) ? f2b(x[r * OBS_ + k]) : (u16)0;
}

__global__ void prep_wcat(const float* __restrict__ W_ih, const float* __restrict__ W_hh,
                          u16* __restrict__ Wcat) {
    const int n = blockIdx.x;        // 1024
    const int k = threadIdx.x;       // 320
    float v;
    if (k < OBS_)      v = W_ih[n * OBS_ + k];
    else if (k < 64)   v = 0.0f;
    else               v = W_hh[n * H_ + (k - 64)];
    Wcat[n * KP_ + k] = f2b(v);
}

__global__ void prep_w1t(const float* __restrict__ W1, u16* __restrict__ W1T) {
    W1T[blockIdx.x * 256 + threadIdx.x] = f2b(W1[threadIdx.x * M1_ + blockIdx.x]);
}

__global__ void prep_w2t(const float* __restrict__ W2, u16* __restrict__ W2T) {
    W2T[blockIdx.x * 512 + threadIdx.x] = f2b(W2[threadIdx.x * M2_ + blockIdx.x]);
}

__global__ void prep_wht(const float* __restrict__ Wm, const float* __restrict__ Ws,
                         u16* __restrict__ WhT) {
    const int n = blockIdx.x, k = threadIdx.x;
    float v = 0.0f;
    if (n < 12)                 v = Wm[k * A_ + n];
    else if (n >= 16 && n < 28) v = Ws[k * A_ + (n - 16)];
    WhT[n * 256 + k] = f2b(v);
}

__global__ void init_h0(const float* __restrict__ h0, u16* __restrict__ hs0) {
    const int i = blockIdx.x * 256 + threadIdx.x;
    hs0[i] = f2b(h0[i]);
}

__global__ void zero_flags(int* __restrict__ f) {
    f[blockIdx.x * 256 + threadIdx.x] = 0;
}

// ---------------------------------------------------------------------------
// Persistent LSTM scan. Grid = 512 blocks (2/CU guaranteed: LDS 59.6 KB,
// launch_bounds(256,2)). Block (bi,ji) owns rows b0..b0+63 x gate-cols
// j0..j0+15 (x4 gates) for ALL timesteps. c state in registers, Wcat
// B-fragments preloaded in registers. Cross-step dep handled by per-row-group
// flag counters (16 blocks per group; blocks stride-32 apart -> same XCD).
// ---------------------------------------------------------------------------
__global__ __launch_bounds__(256, 2) void lstm_scan(
    const u16*  __restrict__ xpad,   // [T][B][64]
    const int*  __restrict__ done,   // [T][B]
    u16*        __restrict__ hs,     // [(T+1)][B][256]
    const float* __restrict__ c0,    // [B][256]
    const u16*  __restrict__ Wcat,   // [1024][320]
    const float* __restrict__ b_ih,
    const float* __restrict__ b_hh,
    int*        __restrict__ flags)  // [T][32]
{
    __shared__ u16   a_sm[64][328];   // 656B row stride (4-bank step)
    __shared__ float g_sm[64][68];
    __shared__ float keep_sm[64];

    const int tid  = threadIdx.x;
    const int lane = tid & 63;
    const int wave = tid >> 6;
    const int wm = wave & 1, wn = wave >> 1;
    const int quad = lane >> 4, l16 = lane & 15;
    const int bi = blockIdx.x & 31;       // row group
    const int ji = blockIdx.x >> 5;       // j tile
    const int b0 = bi * 64, j0 = ji * 16;

    // ---- preload B fragments (constant over t): 20 frags = 80 VGPRs ----
    bf16x8 Bf0[10], Bf1[10];
    {
        const u16* wp0 = Wcat + ((size_t)((wn * 2 + 0) * 256 + j0 + l16)) * KP_ + quad * 8;
        const u16* wp1 = Wcat + ((size_t)((wn * 2 + 1) * 256 + j0 + l16)) * KP_ + quad * 8;
        #pragma unroll
        for (int kt = 0; kt < 10; ++kt) {
            Bf0[kt] = *(const bf16x8*)(wp0 + kt * 32);
            Bf1[kt] = *(const bf16x8*)(wp1 + kt * 32);
        }
    }

    // ---- epilogue role + persistent c registers ----
    const int jj = tid & 15, bq = tid >> 4;
    const int jg = j0 + jj;
    const float bi_b = b_ih[jg]       + b_hh[jg];
    const float bf_b = b_ih[256 + jg] + b_hh[256 + jg];
    const float bg_b = b_ih[512 + jg] + b_hh[512 + jg];
    const float bo_b = b_ih[768 + jg] + b_hh[768 + jg];
    float c_reg[4];
    #pragma unroll
    for (int r = 0; r < 4; ++r)
        c_reg[r] = c0[(size_t)(b0 + bq * 4 + r) * H_ + jg];

    const int srow = tid >> 2;       // staging row 0..63
    const int sseg = tid & 3;

    for (int t = 0; t < T_; ++t) {
        // ---- wait for hs[t] from previous step (same row group only) ----
        if (t > 0) {
            if (tid == 0) {
                while (__hip_atomic_load(&flags[t * 32 + bi], __ATOMIC_RELAXED,
                                         __HIP_MEMORY_SCOPE_AGENT) < 16) {
                    __builtin_amdgcn_s_sleep(1);
                }
            }
        }
        __syncthreads();
        if (t > 0) __builtin_amdgcn_fence(__ATOMIC_ACQUIRE, "agent");

        // ---- stage A tile (one shot, all K=320) ----
        if (tid < 64) keep_sm[tid] = done[t * B_ + b0 + tid] ? 0.0f : 1.0f;
        {
            const u16* xrow = xpad + (size_t)t * B_ * 64 + (size_t)(b0 + srow) * 64;
            uint4 xv0 = *(const uint4*)(xrow + sseg * 8);
            uint4 xv1 = *(const uint4*)(xrow + (sseg + 4) * 8);
            *(uint4*)(&a_sm[srow][sseg * 8])       = xv0;
            *(uint4*)(&a_sm[srow][(sseg + 4) * 8]) = xv1;

            const int dn = done[t * B_ + b0 + srow];
            const u16* hrow = hs + (size_t)t * BH_ + (size_t)(b0 + srow) * H_ + sseg * 64;
            #pragma unroll
            for (int i = 0; i < 8; ++i) {
                uint4 hv = *(const uint4*)(hrow + i * 8);
                if (dn) hv = make_uint4(0u, 0u, 0u, 0u);
                *(uint4*)(&a_sm[srow][64 + sseg * 64 + i * 8]) = hv;
            }
        }
        __syncthreads();

        // ---- 40 MFMA ----
        f32x4 acc00 = {0,0,0,0}, acc01 = {0,0,0,0}, acc10 = {0,0,0,0}, acc11 = {0,0,0,0};
        #pragma unroll
        for (int kt = 0; kt < 10; ++kt) {
            const bf16x8 af0 = *(const bf16x8*)(&a_sm[wm * 32 +  0 + l16][kt * 32 + quad * 8]);
            const bf16x8 af1 = *(const bf16x8*)(&a_sm[wm * 32 + 16 + l16][kt * 32 + quad * 8]);
            acc00 = __builtin_amdgcn_mfma_f32_16x16x32_bf16(af0, Bf0[kt], acc00, 0, 0, 0);
            acc01 = __builtin_amdgcn_mfma_f32_16x16x32_bf16(af0, Bf1[kt], acc01, 0, 0, 0);
            acc10 = __builtin_amdgcn_mfma_f32_16x16x32_bf16(af1, Bf0[kt], acc10, 0, 0, 0);
            acc11 = __builtin_amdgcn_mfma_f32_16x16x32_bf16(af1, Bf1[kt], acc11, 0, 0, 0);
        }

        // ---- accs -> LDS for gate fusion ----
        #pragma unroll
        for (int r = 0; r < 4; ++r) {
            g_sm[wm * 32 +  0 + quad * 4 + r][wn * 32 +  0 + l16] = acc00[r];
            g_sm[wm * 32 +  0 + quad * 4 + r][wn * 32 + 16 + l16] = acc01[r];
            g_sm[wm * 32 + 16 + quad * 4 + r][wn * 32 +  0 + l16] = acc10[r];
            g_sm[wm * 32 + 16 + quad * 4 + r][wn * 32 + 16 + l16] = acc11[r];
        }
        __syncthreads();

        // ---- epilogue: gates -> c (regs), h -> hs[t+1] ----
        #pragma unroll
        for (int r = 0; r < 4; ++r) {
            const int b = bq * 4 + r;
            const float gi = g_sm[b][jj]      + bi_b;
            const float gf = g_sm[b][16 + jj] + bf_b;
            const float gg = g_sm[b][32 + jj] + bg_b;
            const float go = g_sm[b][48 + jj] + bo_b;
            const float cold = c_reg[r] * keep_sm[b];
            const float cn = sigm(gf) * cold + sigm(gi) * tanh_fast(gg);
            c_reg[r] = cn;
            hs[(size_t)(t + 1) * BH_ + (size_t)(b0 + b) * H_ + jg] =
                f2b(sigm(go) * tanh_fast(cn));
        }
        __syncthreads();   // drains all waves' h stores (vmcnt(0) before barrier)

        // ---- publish hs[t+1] for this row group ----
        if (t < T_ - 1 && tid == 0) {
            __hip_atomic_fetch_add(&flags[(t + 1) * 32 + bi], 1,
                                   __ATOMIC_RELEASE, __HIP_MEMORY_SCOPE_AGENT);
        }
    }
}

// ---------------------------------------------------------------------------
// Fused LN -> MLP -> heads, all GEMMs on MFMA. 32 rows per block, 4 waves.
// Round 3: explicit double-buffered weight-fragment prefetch in L1/L2 loops.
// ---------------------------------------------------------------------------
__global__ __launch_bounds__(256, 2) void mlp_mfma(
    const u16*  __restrict__ hs,    // [nrows][256] bf16
    float*      __restrict__ out,   // [nrows][14]
    const float* __restrict__ lng, const float* __restrict__ lnb,
    const u16*  __restrict__ W1T, const float* __restrict__ b1,
    const u16*  __restrict__ W2T, const float* __restrict__ b2,
    const u16*  __restrict__ WhT,
    const float* __restrict__ bm, const float* __restrict__ bs)
{
    __shared__ u16   ybf[32][264];
    __shared__ u16   y1bf[32][520];
    __shared__ float ls[32][12];

    const int tid  = threadIdx.x;
    const int lane = tid & 63;
    const int wave = tid >> 6;
    const int quad = lane >> 4, l16 = lane & 15;
    const int row0 = blockIdx.x * 32;

    // ---- LayerNorm ----
    {
        const float4 gv = *(const float4*)(lng + lane * 4);
        const float4 bv = *(const float4*)(lnb + lane * 4);
        for (int rr = 0; rr < 8; ++rr) {
            const int r = wave * 8 + rr;
            const ushort4 hv = *(const ushort4*)(hs + (size_t)(row0 + r) * H_ + lane * 4);
            const float v0 = b2f(hv.x), v1 = b2f(hv.y), v2 = b2f(hv.z), v3 = b2f(hv.w);
            float s  = v0 + v1 + v2 + v3;
            float ss = v0 * v0 + v1 * v1 + v2 * v2 + v3 * v3;
            #pragma unroll
            for (int off = 32; off > 0; off >>= 1) {
                s  += __shfl_down(s,  off);
                ss += __shfl_down(ss, off);
            }
            s = __shfl(s, 0); ss = __shfl(ss, 0);
            const float mu   = s * (1.0f / 256.0f);
            const float rstd = rsqrtf(ss * (1.0f / 256.0f) - mu * mu + 1e-5f);
            ushort4 o;
            o.x = f2b((v0 - mu) * rstd * gv.x + bv.x);
            o.y = f2b((v1 - mu) * rstd * gv.y + bv.y);
            o.z = f2b((v2 - mu) * rstd * gv.z + bv.z);
            o.w = f2b((v3 - mu) * rstd * gv.w + bv.w);
            *(ushort4*)(&ybf[r][lane * 4]) = o;
        }
    }
    __syncthreads();

    // ---- Layer 1 with weight prefetch ----
    {
        f32x4 acc[2][8];
        #pragma unroll
        for (int i = 0; i < 2; ++i)
            #pragma unroll
            for (int j = 0; j < 8; ++j) acc[i][j] = (f32x4){0,0,0,0};
        const u16* wpB = W1T + (size_t)(wave * 128 + l16) * 256 + quad * 8;
        bf16x8 bwc[8], bwn[8];
        #pragma unroll
        for (int j = 0; j < 8; ++j) bwc[j] = *(const bf16x8*)(wpB + (size_t)j * 16 * 256);
        #pragma unroll
        for (int kt = 0; kt < 8; ++kt) {
            const int k0 = kt * 32;
            if (kt < 7) {
                #pragma unroll
                for (int j = 0; j < 8; ++j)
                    bwn[j] = *(const bf16x8*)(wpB + (size_t)j * 16 * 256 + k0 + 32);
            }
            const bf16x8 af0 = *(const bf16x8*)(&ybf[l16][k0 + quad * 8]);
            const bf16x8 af1 = *(const bf16x8*)(&ybf[16 + l16][k0 + quad * 8]);
            #pragma unroll
            for (int j = 0; j < 8; ++j) {
                acc[0][j] = __builtin_amdgcn_mfma_f32_16x16x32_bf16(af0, bwc[j], acc[0][j], 0, 0, 0);
                acc[1][j] = __builtin_amdgcn_mfma_f32_16x16x32_bf16(af1, bwc[j], acc[1][j], 0, 0, 0);
            }
            #pragma unroll
            for (int j = 0; j < 8; ++j) bwc[j] = bwn[j];
        }
        #pragma unroll
        for (int j = 0; j < 8; ++j) {
            const int n = wave * 128 + j * 16 + l16;
            const float bb = b1[n];
            #pragma unroll
            for (int i = 0; i < 2; ++i)
                #pragma unroll
                for (int r = 0; r < 4; ++r)
                    y1bf[i * 16 + quad * 4 + r][n] = f2b(elu(acc[i][j][r] + bb));
        }
    }
    __syncthreads();

    // ---- Layer 2 with weight prefetch ----
    {
        f32x4 acc[2][4];
        #pragma unroll
        for (int i = 0; i < 2; ++i)
            #pragma unroll
            for (int j = 0; j < 4; ++j) acc[i][j] = (f32x4){0,0,0,0};
        const u16* wpB = W2T + (size_t)(wave * 64 + l16) * 512 + quad * 8;
        bf16x8 bwc[4], bwn[4];
        #pragma unroll
        for (int j = 0; j < 4; ++j) bwc[j] = *(const bf16x8*)(wpB + (size_t)j * 16 * 512);
        #pragma unroll
        for (int kt = 0; kt < 16; ++kt) {
            const int k0 = kt * 32;
            if (kt < 15) {
                #pragma unroll
                for (int j = 0; j < 4; ++j)
                    bwn[j] = *(const bf16x8*)(wpB + (size_t)j * 16 * 512 + k0 + 32);
            }
            const bf16x8 af0 = *(const bf16x8*)(&y1bf[l16][k0 + quad * 8]);
            const bf16x8 af1 = *(const bf16x8*)(&y1bf[16 + l16][k0 + quad * 8]);
            #pragma unroll
            for (int j = 0; j < 4; ++j) {
                acc[0][j] = __builtin_amdgcn_mfma_f32_16x16x32_bf16(af0, bwc[j], acc[0][j], 0, 0, 0);
                acc[1][j] = __builtin_amdgcn_mfma_f32_16x16x32_bf16(af1, bwc[j], acc[1][j], 0, 0, 0);
            }
            #pragma unroll
            for (int j = 0; j < 4; ++j) bwc[j] = bwn[j];
        }
        #pragma unroll
        for (int j = 0; j < 4; ++j) {
            const int n = wave * 64 + j * 16 + l16;
            const float bb = b2[n];
            #pragma unroll
            for (int i = 0; i < 2; ++i)
                #pragma unroll
                for (int r = 0; r < 4; ++r)
                    ybf[i * 16 + quad * 4 + r][n] = f2b(elu(acc[i][j][r] + bb));
        }
    }
    __syncthreads();

    // ---- Heads ----
    if (wave < 2) {
        f32x4 a0 = {0,0,0,0}, a1 = {0,0,0,0};
        const u16* wp = WhT + (size_t)(wave * 16 + l16) * 256 + quad * 8;
        for (int kt = 0; kt < 8; ++kt) {
            const int k0 = kt * 32;
            const bf16x8 af0 = *(const bf16x8*)(&ybf[l16][k0 + quad * 8]);
            const bf16x8 af1 = *(const bf16x8*)(&ybf[16 + l16][k0 + quad * 8]);
            const bf16x8 bw  = *(const bf16x8*)(wp + k0);
            a0 = __builtin_amdgcn_mfma_f32_16x16x32_bf16(af0, bw, a0, 0, 0, 0);
            a1 = __builtin_amdgcn_mfma_f32_16x16x32_bf16(af1, bw, a1, 0, 0, 0);
        }
        if (l16 < 12) {
            f32x4 aa[2] = {a0, a1};
            if (wave == 0) {
                const float bb = bm[l16];
                #pragma unroll
                for (int i = 0; i < 2; ++i)
                    #pragma unroll
                    for (int r = 0; r < 4; ++r) {
                        const int m = i * 16 + quad * 4 + r;
                        out[(size_t)(row0 + m) * 14 + l16] = aa[i][r] + bb;
                    }
            } else {
                const float bb = bs[l16];
                #pragma unroll
                for (int i = 0; i < 2; ++i)
                    #pragma unroll
                    for (int r = 0; r < 4; ++r) {
                        const int m = i * 16 + quad * 4 + r;
                        ls[m][l16] = fminf(fmaxf(aa[i][r] + bb, -5.0f), 2.0f);
                    }
            }
        }
    }
    __syncthreads();
    if (tid < 32) {
        float s = 0.0f;
        #pragma unroll
        for (int q = 0; q < 12; ++q) s += ls[tid][q];
        const float LOG2PI = 1.8378770664093453f;
        out[(size_t)(row0 + tid) * 14 + 12] = -s - 6.0f * LOG2PI;
        out[(size_t)(row0 + tid) * 14 + 13] =  s + 6.0f + 6.0f * LOG2PI;
    }
}

// ---------------------------------------------------------------------------
extern "C" void kernel_launch(void* const* d_in, const int* in_sizes, int n_in,
                              void* d_out, int out_size, void* d_ws, size_t ws_size,
                              hipStream_t stream) {
    (void)in_sizes; (void)n_in; (void)out_size; (void)ws_size;
    const float* x    = (const float*)d_in[0];
    const int*   done = (const int*)  d_in[1];
    const float* h0   = (const float*)d_in[2];
    const float* c0   = (const float*)d_in[3];
    const float* W_ih = (const float*)d_in[4];
    const float* W_hh = (const float*)d_in[5];
    const float* b_ih = (const float*)d_in[6];
    const float* b_hh = (const float*)d_in[7];
    const float* lng  = (const float*)d_in[8];
    const float* lnb  = (const float*)d_in[9];
    const float* W1   = (const float*)d_in[10];
    const float* b1   = (const float*)d_in[11];
    const float* W2   = (const float*)d_in[12];
    const float* b2   = (const float*)d_in[13];
    const float* Wm   = (const float*)d_in[14];
    const float* bm   = (const float*)d_in[15];
    const float* Ws   = (const float*)d_in[16];
    const float* bs   = (const float*)d_in[17];
    float* out = (float*)d_out;

    // workspace carve (~35 MB; ws_size >= 135 MB confirmed)
    unsigned char* p = (unsigned char*)d_ws;
    u16* hs    = (u16*)p;              p += (size_t)(T_ + 1) * BH_ * 2;
    u16* xpad  = (u16*)p;              p += (size_t)T_ * B_ * 64 * 2;
    u16* Wcat  = (u16*)p;              p += (size_t)1024 * KP_ * 2;
    u16* W1T   = (u16*)p;              p += (size_t)M1_ * H_ * 2;
    u16* W2T   = (u16*)p;              p += (size_t)M2_ * M1_ * 2;
    u16* WhT   = (u16*)p;              p += (size_t)32 * H_ * 2;
    int* flags = (int*)p;              p += (size_t)T_ * 32 * 4;

    prep_xpad<<<(T_ * B_ * 64) / 256, 256, 0, stream>>>(x, xpad);
    prep_wcat<<<1024, KP_, 0, stream>>>(W_ih, W_hh, Wcat);
    prep_w1t<<<M1_, 256, 0, stream>>>(W1, W1T);
    prep_w2t<<<M2_, 512, 0, stream>>>(W2, W2T);
    prep_wht<<<32, 256, 0, stream>>>(Wm, Ws, WhT);
    init_h0<<<BH_ / 256, 256, 0, stream>>>(h0, hs);
    zero_flags<<<(T_ * 32) / 256, 256, 0, stream>>>(flags);

    lstm_scan<<<512, 256, 0, stream>>>(xpad, done, hs, c0, Wcat, b_ih, b_hh, flags);

    mlp_mfma<<<(T_ * B_) / 32, 256, 0, stream>>>(
        hs + BH_, out, lng, lnb, W1T, b1, W2T, b2, WhT, bm, bs);
}

// Round 4
// 1064.202 us; speedup vs baseline: 2.3958x; 2.3958x over previous
//
#include <hip/hip_runtime.h>
#include <hip/hip_bf16.h>
#include <math.h>

#define T_   64
#define B_   2048
#define OBS_ 48
#define H_   256
#define M1_  512
#define M2_  256
#define A_   12
#define BH_  (B_ * H_)
#define KP_  320   // padded K for scan: 64 (x, padded from 48) + 256 (h)

typedef unsigned short u16;
typedef __attribute__((ext_vector_type(8))) short bf16x8;
typedef __attribute__((ext_vector_type(4))) float f32x4;

static __device__ __forceinline__ u16 f2b(float f) {
    __hip_bfloat16 h = __float2bfloat16(f);
    return *reinterpret_cast<u16*>(&h);
}
static __device__ __forceinline__ float b2f(u16 u) {
    union { unsigned u32; float f; } v; v.u32 = ((unsigned)u) << 16; return v.f;
}
static __device__ __forceinline__ float sigm(float x) {
    return 1.0f / (1.0f + __expf(-x));
}
static __device__ __forceinline__ float tanh_fast(float x) {
    x = fminf(fmaxf(x, -15.0f), 15.0f);
    float e = __expf(2.0f * x);
    return (e - 1.0f) / (e + 1.0f);
}
static __device__ __forceinline__ float elu(float x) {
    return x > 0.0f ? x : (__expf(x) - 1.0f);
}

// ---------------------------------------------------------------------------
// Pre-pass kernels
// ---------------------------------------------------------------------------
__global__ void prep_xpad(const float* __restrict__ x, u16* __restrict__ xpad) {
    const int i = blockIdx.x * 256 + threadIdx.x;   // over T*B*64
    const int r = i >> 6, k = i & 63;
    xpad[i] = (k < OBS_) ? f2b(x[r * OBS_ + k]) : (u16)0;
}

__global__ void prep_wcat(const float* __restrict__ W_ih, const float* __restrict__ W_hh,
                          u16* __restrict__ Wcat) {
    const int n = blockIdx.x;        // 1024
    const int k = threadIdx.x;       // 320
    float v;
    if (k < OBS_)      v = W_ih[n * OBS_ + k];
    else if (k < 64)   v = 0.0f;
    else               v = W_hh[n * H_ + (k - 64)];
    Wcat[n * KP_ + k] = f2b(v);
}

__global__ void prep_w1t(const float* __restrict__ W1, u16* __restrict__ W1T) {
    W1T[blockIdx.x * 256 + threadIdx.x] = f2b(W1[threadIdx.x * M1_ + blockIdx.x]);
}

__global__ void prep_w2t(const float* __restrict__ W2, u16* __restrict__ W2T) {
    W2T[blockIdx.x * 512 + threadIdx.x] = f2b(W2[threadIdx.x * M2_ + blockIdx.x]);
}

__global__ void prep_wht(const float* __restrict__ Wm, const float* __restrict__ Ws,
                         u16* __restrict__ WhT) {
    const int n = blockIdx.x, k = threadIdx.x;
    float v = 0.0f;
    if (n < 12)                 v = Wm[k * A_ + n];
    else if (n >= 16 && n < 28) v = Ws[k * A_ + (n - 16)];
    WhT[n * 256 + k] = f2b(v);
}

__global__ void init_state2(const float* __restrict__ h0, const float* __restrict__ c0,
                            u16* __restrict__ hs0, float* __restrict__ Cst) {
    const int i = blockIdx.x * 256 + threadIdx.x;
    hs0[i] = f2b(h0[i]);
    Cst[i] = c0[i];
}

// ---------------------------------------------------------------------------
// LSTM step v4 (one dispatch per timestep; kernel boundary = global barrier).
// Grid (32,16): block tile = 64 b-rows x (4 gates x 16 j), 4 waves of 32x32.
// - ONE staging barrier pair per step: whole K=320 A-tile staged at once into
//   XOR-swizzled LDS (16B chunk c at row r lives at chunk c^(r&7)) -> uniform
//   bank spread for both the staging writes and the ds_read_b128 frag reads.
// - B fragments (Wcat) preloaded into 80 VGPRs once per dispatch (L2 hits).
// - c in fp32 global (Cst), h ring in bf16 hs.
// ---------------------------------------------------------------------------
#define ASM_(row, chunk) (a_sm + (size_t)(row) * 320 + (size_t)(((chunk) ^ ((row) & 7)) << 3))

__global__ __launch_bounds__(256, 2) void lstm_step4(
    const u16*  __restrict__ xpad_t,  // [B][64]
    const int*  __restrict__ done_t,  // [B]
    const u16*  __restrict__ Hin,     // [B][256] bf16
    u16*        __restrict__ Hout,    // [B][256] bf16
    float*      __restrict__ Cst,     // [B][256] fp32, in-place
    const u16*  __restrict__ Wcat,    // [1024][320]
    const float* __restrict__ b_ih,
    const float* __restrict__ b_hh)
{
    __shared__ u16   a_sm[64 * 320];   // 40 KB, XOR-swizzled
    __shared__ float g_sm[64][68];     // 17.4 KB
    __shared__ float keep_sm[64];

    const int tid  = threadIdx.x;
    const int lane = tid & 63;
    const int wave = tid >> 6;
    const int wm = wave & 1, wn = wave >> 1;
    const int quad = lane >> 4, l16 = lane & 15;
    const int b0 = blockIdx.x * 64;
    const int j0 = blockIdx.y * 16;

    // ---- preload B fragments (20 frags = 80 VGPRs; Wcat is L2-resident) ----
    bf16x8 Bf0[10], Bf1[10];
    {
        const u16* wp0 = Wcat + ((size_t)((wn * 2 + 0) * 256 + j0 + l16)) * KP_ + quad * 8;
        const u16* wp1 = Wcat + ((size_t)((wn * 2 + 1) * 256 + j0 + l16)) * KP_ + quad * 8;
        #pragma unroll
        for (int kt = 0; kt < 10; ++kt) {
            Bf0[kt] = *(const bf16x8*)(wp0 + kt * 32);
            Bf1[kt] = *(const bf16x8*)(wp1 + kt * 32);
        }
    }

    // ---- stage A tile: whole K=320 in one shot ----
    if (tid < 64) keep_sm[tid] = done_t[b0 + tid] ? 0.0f : 1.0f;
    {
        const int srow = tid >> 2;     // 0..63
        const int sseg = tid & 3;      // 0..3
        const u16* xrow = xpad_t + (size_t)(b0 + srow) * 64;
        const uint4 xv0 = *(const uint4*)(xrow + sseg * 8);         // chunk sseg
        const uint4 xv1 = *(const uint4*)(xrow + (sseg + 4) * 8);   // chunk sseg+4
        *(uint4*)ASM_(srow, sseg)     = xv0;
        *(uint4*)ASM_(srow, sseg + 4) = xv1;

        const int dn = done_t[b0 + srow];
        const u16* hrow = Hin + (size_t)(b0 + srow) * H_ + sseg * 64;
        #pragma unroll
        for (int i = 0; i < 8; ++i) {
            uint4 hv = *(const uint4*)(hrow + i * 8);
            if (dn) hv = make_uint4(0u, 0u, 0u, 0u);
            *(uint4*)ASM_(srow, 8 + sseg * 8 + i) = hv;
        }
    }
    __syncthreads();

    // ---- 40 MFMA per wave ----
    f32x4 acc00 = {0,0,0,0}, acc01 = {0,0,0,0}, acc10 = {0,0,0,0}, acc11 = {0,0,0,0};
    #pragma unroll
    for (int kt = 0; kt < 10; ++kt) {
        const bf16x8 af0 = *(const bf16x8*)ASM_(wm * 32 +  0 + l16, kt * 4 + quad);
        const bf16x8 af1 = *(const bf16x8*)ASM_(wm * 32 + 16 + l16, kt * 4 + quad);
        acc00 = __builtin_amdgcn_mfma_f32_16x16x32_bf16(af0, Bf0[kt], acc00, 0, 0, 0);
        acc01 = __builtin_amdgcn_mfma_f32_16x16x32_bf16(af0, Bf1[kt], acc01, 0, 0, 0);
        acc10 = __builtin_amdgcn_mfma_f32_16x16x32_bf16(af1, Bf0[kt], acc10, 0, 0, 0);
        acc11 = __builtin_amdgcn_mfma_f32_16x16x32_bf16(af1, Bf1[kt], acc11, 0, 0, 0);
    }

    // ---- accs -> LDS for cross-wave gate fusion (D: col=l16, row=quad*4+r) ----
    #pragma unroll
    for (int r = 0; r < 4; ++r) {
        g_sm[wm * 32 +  0 + quad * 4 + r][wn * 32 +  0 + l16] = acc00[r];
        g_sm[wm * 32 +  0 + quad * 4 + r][wn * 32 + 16 + l16] = acc01[r];
        g_sm[wm * 32 + 16 + quad * 4 + r][wn * 32 +  0 + l16] = acc10[r];
        g_sm[wm * 32 + 16 + quad * 4 + r][wn * 32 + 16 + l16] = acc11[r];
    }
    __syncthreads();

    // ---- epilogue: gates -> c (fp32 global), h -> Hout (bf16) ----
    const int jj = tid & 15, bq = tid >> 4;
    const int jg = j0 + jj;
    const float bi_b = b_ih[jg]       + b_hh[jg];
    const float bf_b = b_ih[256 + jg] + b_hh[256 + jg];
    const float bg_b = b_ih[512 + jg] + b_hh[512 + jg];
    const float bo_b = b_ih[768 + jg] + b_hh[768 + jg];
    #pragma unroll
    for (int r = 0; r < 4; ++r) {
        const int b = bq * 4 + r;
        const float gi = g_sm[b][jj]      + bi_b;
        const float gf = g_sm[b][16 + jj] + bf_b;
        const float gg = g_sm[b][32 + jj] + bg_b;
        const float go = g_sm[b][48 + jj] + bo_b;
        const size_t idx = (size_t)(b0 + b) * H_ + jg;
        const float cold = Cst[idx] * keep_sm[b];
        const float cn = sigm(gf) * cold + sigm(gi) * tanh_fast(gg);
        Cst[idx] = cn;
        Hout[idx] = f2b(sigm(go) * tanh_fast(cn));
    }
}

// ---------------------------------------------------------------------------
// Fused LN -> MLP -> heads, all GEMMs on MFMA. 32 rows per block, 4 waves.
// Double-buffered weight-fragment prefetch in L1/L2 loops (round 3).
// ---------------------------------------------------------------------------
__global__ __launch_bounds__(256, 2) void mlp_mfma(
    const u16*  __restrict__ hs,    // [nrows][256] bf16
    float*      __restrict__ out,   // [nrows][14]
    const float* __restrict__ lng, const float* __restrict__ lnb,
    const u16*  __restrict__ W1T, const float* __restrict__ b1,
    const u16*  __restrict__ W2T, const float* __restrict__ b2,
    const u16*  __restrict__ WhT,
    const float* __restrict__ bm, const float* __restrict__ bs)
{
    __shared__ u16   ybf[32][264];
    __shared__ u16   y1bf[32][520];
    __shared__ float ls[32][12];

    const int tid  = threadIdx.x;
    const int lane = tid & 63;
    const int wave = tid >> 6;
    const int quad = lane >> 4, l16 = lane & 15;
    const int row0 = blockIdx.x * 32;

    // ---- LayerNorm ----
    {
        const float4 gv = *(const float4*)(lng + lane * 4);
        const float4 bv = *(const float4*)(lnb + lane * 4);
        for (int rr = 0; rr < 8; ++rr) {
            const int r = wave * 8 + rr;
            const ushort4 hv = *(const ushort4*)(hs + (size_t)(row0 + r) * H_ + lane * 4);
            const float v0 = b2f(hv.x), v1 = b2f(hv.y), v2 = b2f(hv.z), v3 = b2f(hv.w);
            float s  = v0 + v1 + v2 + v3;
            float ss = v0 * v0 + v1 * v1 + v2 * v2 + v3 * v3;
            #pragma unroll
            for (int off = 32; off > 0; off >>= 1) {
                s  += __shfl_down(s,  off);
                ss += __shfl_down(ss, off);
            }
            s = __shfl(s, 0); ss = __shfl(ss, 0);
            const float mu   = s * (1.0f / 256.0f);
            const float rstd = rsqrtf(ss * (1.0f / 256.0f) - mu * mu + 1e-5f);
            ushort4 o;
            o.x = f2b((v0 - mu) * rstd * gv.x + bv.x);
            o.y = f2b((v1 - mu) * rstd * gv.y + bv.y);
            o.z = f2b((v2 - mu) * rstd * gv.z + bv.z);
            o.w = f2b((v3 - mu) * rstd * gv.w + bv.w);
            *(ushort4*)(&ybf[r][lane * 4]) = o;
        }
    }
    __syncthreads();

    // ---- Layer 1 with weight prefetch ----
    {
        f32x4 acc[2][8];
        #pragma unroll
        for (int i = 0; i < 2; ++i)
            #pragma unroll
            for (int j = 0; j < 8; ++j) acc[i][j] = (f32x4){0,0,0,0};
        const u16* wpB = W1T + (size_t)(wave * 128 + l16) * 256 + quad * 8;
        bf16x8 bwc[8], bwn[8];
        #pragma unroll
        for (int j = 0; j < 8; ++j) bwc[j] = *(const bf16x8*)(wpB + (size_t)j * 16 * 256);
        #pragma unroll
        for (int kt = 0; kt < 8; ++kt) {
            const int k0 = kt * 32;
            if (kt < 7) {
                #pragma unroll
                for (int j = 0; j < 8; ++j)
                    bwn[j] = *(const bf16x8*)(wpB + (size_t)j * 16 * 256 + k0 + 32);
            }
            const bf16x8 af0 = *(const bf16x8*)(&ybf[l16][k0 + quad * 8]);
            const bf16x8 af1 = *(const bf16x8*)(&ybf[16 + l16][k0 + quad * 8]);
            #pragma unroll
            for (int j = 0; j < 8; ++j) {
                acc[0][j] = __builtin_amdgcn_mfma_f32_16x16x32_bf16(af0, bwc[j], acc[0][j], 0, 0, 0);
                acc[1][j] = __builtin_amdgcn_mfma_f32_16x16x32_bf16(af1, bwc[j], acc[1][j], 0, 0, 0);
            }
            #pragma unroll
            for (int j = 0; j < 8; ++j) bwc[j] = bwn[j];
        }
        #pragma unroll
        for (int j = 0; j < 8; ++j) {
            const int n = wave * 128 + j * 16 + l16;
            const float bb = b1[n];
            #pragma unroll
            for (int i = 0; i < 2; ++i)
                #pragma unroll
                for (int r = 0; r < 4; ++r)
                    y1bf[i * 16 + quad * 4 + r][n] = f2b(elu(acc[i][j][r] + bb));
        }
    }
    __syncthreads();

    // ---- Layer 2 with weight prefetch ----
    {
        f32x4 acc[2][4];
        #pragma unroll
        for (int i = 0; i < 2; ++i)
            #pragma unroll
            for (int j = 0; j < 4; ++j) acc[i][j] = (f32x4){0,0,0,0};
        const u16* wpB = W2T + (size_t)(wave * 64 + l16) * 512 + quad * 8;
        bf16x8 bwc[4], bwn[4];
        #pragma unroll
        for (int j = 0; j < 4; ++j) bwc[j] = *(const bf16x8*)(wpB + (size_t)j * 16 * 512);
        #pragma unroll
        for (int kt = 0; kt < 16; ++kt) {
            const int k0 = kt * 32;
            if (kt < 15) {
                #pragma unroll
                for (int j = 0; j < 4; ++j)
                    bwn[j] = *(const bf16x8*)(wpB + (size_t)j * 16 * 512 + k0 + 32);
            }
            const bf16x8 af0 = *(const bf16x8*)(&y1bf[l16][k0 + quad * 8]);
            const bf16x8 af1 = *(const bf16x8*)(&y1bf[16 + l16][k0 + quad * 8]);
            #pragma unroll
            for (int j = 0; j < 4; ++j) {
                acc[0][j] = __builtin_amdgcn_mfma_f32_16x16x32_bf16(af0, bwc[j], acc[0][j], 0, 0, 0);
                acc[1][j] = __builtin_amdgcn_mfma_f32_16x16x32_bf16(af1, bwc[j], acc[1][j], 0, 0, 0);
            }
            #pragma unroll
            for (int j = 0; j < 4; ++j) bwc[j] = bwn[j];
        }
        #pragma unroll
        for (int j = 0; j < 4; ++j) {
            const int n = wave * 64 + j * 16 + l16;
            const float bb = b2[n];
            #pragma unroll
            for (int i = 0; i < 2; ++i)
                #pragma unroll
                for (int r = 0; r < 4; ++r)
                    ybf[i * 16 + quad * 4 + r][n] = f2b(elu(acc[i][j][r] + bb));
        }
    }
    __syncthreads();

    // ---- Heads ----
    if (wave < 2) {
        f32x4 a0 = {0,0,0,0}, a1 = {0,0,0,0};
        const u16* wp = WhT + (size_t)(wave * 16 + l16) * 256 + quad * 8;
        for (int kt = 0; kt < 8; ++kt) {
            const int k0 = kt * 32;
            const bf16x8 af0 = *(const bf16x8*)(&ybf[l16][k0 + quad * 8]);
            const bf16x8 af1 = *(const bf16x8*)(&ybf[16 + l16][k0 + quad * 8]);
            const bf16x8 bw  = *(const bf16x8*)(wp + k0);
            a0 = __builtin_amdgcn_mfma_f32_16x16x32_bf16(af0, bw, a0, 0, 0, 0);
            a1 = __builtin_amdgcn_mfma_f32_16x16x32_bf16(af1, bw, a1, 0, 0, 0);
        }
        if (l16 < 12) {
            f32x4 aa[2] = {a0, a1};
            if (wave == 0) {
                const float bb = bm[l16];
                #pragma unroll
                for (int i = 0; i < 2; ++i)
                    #pragma unroll
                    for (int r = 0; r < 4; ++r) {
                        const int m = i * 16 + quad * 4 + r;
                        out[(size_t)(row0 + m) * 14 + l16] = aa[i][r] + bb;
                    }
            } else {
                const float bb = bs[l16];
                #pragma unroll
                for (int i = 0; i < 2; ++i)
                    #pragma unroll
                    for (int r = 0; r < 4; ++r) {
                        const int m = i * 16 + quad * 4 + r;
                        ls[m][l16] = fminf(fmaxf(aa[i][r] + bb, -5.0f), 2.0f);
                    }
            }
        }
    }
    __syncthreads();
    if (tid < 32) {
        float s = 0.0f;
        #pragma unroll
        for (int q = 0; q < 12; ++q) s += ls[tid][q];
        const float LOG2PI = 1.8378770664093453f;
        out[(size_t)(row0 + tid) * 14 + 12] = -s - 6.0f * LOG2PI;
        out[(size_t)(row0 + tid) * 14 + 13] =  s + 6.0f + 6.0f * LOG2PI;
    }
}

// ---------------------------------------------------------------------------
extern "C" void kernel_launch(void* const* d_in, const int* in_sizes, int n_in,
                              void* d_out, int out_size, void* d_ws, size_t ws_size,
                              hipStream_t stream) {
    (void)in_sizes; (void)n_in; (void)out_size; (void)ws_size;
    const float* x    = (const float*)d_in[0];
    const int*   done = (const int*)  d_in[1];
    const float* h0   = (const float*)d_in[2];
    const float* c0   = (const float*)d_in[3];
    const float* W_ih = (const float*)d_in[4];
    const float* W_hh = (const float*)d_in[5];
    const float* b_ih = (const float*)d_in[6];
    const float* b_hh = (const float*)d_in[7];
    const float* lng  = (const float*)d_in[8];
    const float* lnb  = (const float*)d_in[9];
    const float* W1   = (const float*)d_in[10];
    const float* b1   = (const float*)d_in[11];
    const float* W2   = (const float*)d_in[12];
    const float* b2   = (const float*)d_in[13];
    const float* Wm   = (const float*)d_in[14];
    const float* bm   = (const float*)d_in[15];
    const float* Ws   = (const float*)d_in[16];
    const float* bs   = (const float*)d_in[17];
    float* out = (float*)d_out;

    // workspace carve (~37 MB; ws_size >= 135 MB confirmed)
    unsigned char* p = (unsigned char*)d_ws;
    u16* hs    = (u16*)p;              p += (size_t)(T_ + 1) * BH_ * 2;
    u16* xpad  = (u16*)p;              p += (size_t)T_ * B_ * 64 * 2;
    u16* Wcat  = (u16*)p;              p += (size_t)1024 * KP_ * 2;
    u16* W1T   = (u16*)p;              p += (size_t)M1_ * H_ * 2;
    u16* W2T   = (u16*)p;              p += (size_t)M2_ * M1_ * 2;
    u16* WhT   = (u16*)p;              p += (size_t)32 * H_ * 2;
    float* Cst = (float*)p;            p += (size_t)BH_ * 4;

    prep_xpad<<<(T_ * B_ * 64) / 256, 256, 0, stream>>>(x, xpad);
    prep_wcat<<<1024, KP_, 0, stream>>>(W_ih, W_hh, Wcat);
    prep_w1t<<<M1_, 256, 0, stream>>>(W1, W1T);
    prep_w2t<<<M2_, 512, 0, stream>>>(W2, W2T);
    prep_wht<<<32, 256, 0, stream>>>(Wm, Ws, WhT);
    init_state2<<<BH_ / 256, 256, 0, stream>>>(h0, c0, hs, Cst);

    for (int t = 0; t < T_; ++t) {
        lstm_step4<<<dim3(32, 16), 256, 0, stream>>>(
            xpad + (size_t)t * B_ * 64,
            done + (size_t)t * B_,
            hs + (size_t)t * BH_,
            hs + (size_t)(t + 1) * BH_,
            Cst, Wcat, b_ih, b_hh);
    }

    mlp_mfma<<<(T_ * B_) / 32, 256, 0, stream>>>(
        hs + BH_, out, lng, lnb, W1T, b1, W2T, b2, WhT, bm, bs);
}